// Round 8
// baseline (200.545 us; speedup 1.0000x reference)
//
#include <hip/hip_runtime.h>
#include <math.h>

// ---------------------------------------------------------------------------
// KAN-Conv CIFAR net on gfx950, round 8: ONE mega-kernel, one block per image.
// h1/h2/h3 live in LDS; conv structured as thread=conv-position, wave=channel
// (fh wave-uniform -> weights via SCALAR loads, s-operand v_fmac), act read
// from LDS once per tap and reused across all O channels. Channel reduction
// via chunked LDS reduce; maxpool via in-wave shfl_xor. 256 blocks x 1024
// threads = 16 waves/CU (4/SIMD). LDS pool = 64 KB exactly:
//   [0..12800)  act tile (padded parity float4 planes) / reduce / partials
//   [12800)     h1 [8][16][16] = 2048 f
//   [14848)     h2 [16][8][8]  = 1024 f   (L3 act extends to 14208 < 14848,
//   [15872)     h3 [32][4][4]  =  512 f    clobbering dead h1 - by design)
// ---------------------------------------------------------------------------

#define NTHREADS 1024
#define H1_OFF 12800
#define H2_OFF 14848
#define H3_OFF 15872

__device__ __forceinline__ void bspline_basis(float x, float bs[6]) {
    const float h = 2.0f / 3.0f;
    float g[10];
#pragma unroll
    for (int i = 0; i < 10; ++i) g[i] = (float)(i - 3) * h - 1.0f;
    float b[9];
#pragma unroll
    for (int i = 0; i < 9; ++i) b[i] = (x >= g[i] && x < g[i + 1]) ? 1.0f : 0.0f;
#pragma unroll
    for (int j = 1; j <= 3; ++j) {
        const float inv_d = 1.0f / ((float)j * h);
#pragma unroll
        for (int i = 0; i + j < 9; ++i) {
            float left  = (x - g[i]) * inv_d;
            float right = (g[i + j + 1] - x) * inv_d;
            b[i] = left * b[i] + right * b[i + 1];
        }
    }
#pragma unroll
    for (int i = 0; i < 6; ++i) bs[i] = b[i];
}

// Fuse {base_w, spline_w*scaler} into 8-float records for all three layers.
__global__ __launch_bounds__(256) void prep_weights(
        const float* __restrict__ bw1, const float* __restrict__ sw1, const float* __restrict__ sc1,
        const float* __restrict__ bw2, const float* __restrict__ sw2, const float* __restrict__ sc2,
        const float* __restrict__ bw3, const float* __restrict__ sw3, const float* __restrict__ sc3,
        float* __restrict__ w1, float* __restrict__ w2, float* __restrict__ w3) {
    int i = blockIdx.x * blockDim.x + threadIdx.x;
    const float *bw, *sw, *sc;
    float* dst;
    int j;
    if (i < 216)       { bw = bw1; sw = sw1; sc = sc1; dst = w1; j = i; }
    else if (i < 1368) { bw = bw2; sw = sw2; sc = sc2; dst = w2; j = i - 216; }
    else if (i < 5976) { bw = bw3; sw = sw3; sc = sc3; dst = w3; j = i - 1368; }
    else return;
    float s = sc[j];
    float4* o = (float4*)(dst + (size_t)j * 8);
    o[0] = make_float4(bw[j], sw[j * 6 + 0] * s, sw[j * 6 + 1] * s, sw[j * 6 + 2] * s);
    o[1] = make_float4(sw[j * 6 + 3] * s, sw[j * 6 + 4] * s, sw[j * 6 + 5] * s, 0.0f);
}

// One conv+pool layer executed by the whole block from/to LDS.
// thread = (fh = channel, pos = conv position in strip); weights scalar-loaded.
// CST/RST/CP: padded act layout strides (float4 units), hand-verified to fit.
template <int C, int O, int H, int W, int VS, int CST, int RST, int CP, bool SG>
__device__ __forceinline__ void conv_phase(float* pool,
        const float* __restrict__ src_g, int src_off,
        const float* __restrict__ wrec, int h_off, int tid) {
    constexpr int PH = H / 2, PW = W / 2;
    constexpr int CR = H / VS;             // conv rows per strip (8 for all)
    constexpr int R  = CR + 2;             // tile rows incl. halo (10)
    constexpr int TC = W + 2;              // tile cols incl. halo
    constexpr int F  = C * 9;
    constexpr int POS = CR * W;            // positions per strip
    constexpr int FS  = C;                 // one channel per fh group
    constexpr int NA  = POS * FS;          // active threads
    constexpr int PLANE = C * CST;         // float4 per parity plane
    static_assert(POS % 64 == 0, "fh must be wave-uniform");
    static_assert(NA <= NTHREADS, "block fits");
    static_assert(O % 8 == 0, "reduce round size");
    static_assert(RST >= TC + 1 && CST >= R * RST, "padding");

    float4* actp = (float4*)pool;
    const int lane = tid & 63;
    const int pos = tid % POS;
    const bool active = tid < NA;
    const int fh = __builtin_amdgcn_readfirstlane(tid / POS);  // channel, SGPR
    const int y = pos / W, xx = pos % W;

#pragma unroll 1
    for (int v = 0; v < VS; ++v) {
        __syncthreads();   // prior reduce-reads / h-writes done before restage
        const int r0 = v * CR - 1;
        for (int i = tid; i < C * R * TC; i += NTHREADS) {
            const int cc  = i / (R * TC);
            const int rr  = (i / TC) % R;
            const int col = i % TC;
            const int gr = r0 + rr, gc = col - 1;
            float val = 0.f;
            if ((unsigned)gr < (unsigned)H && (unsigned)gc < (unsigned)W)
                val = SG ? src_g[(cc * H + gr) * W + gc]
                         : pool[src_off + (cc * H + gr) * W + gc];
            const float silu = val / (1.f + __expf(-val));
            float bs[6];
            bspline_basis(val, bs);
            const int idx = cc * CST + rr * RST + (col & 1) * CP + (col >> 1);
            actp[idx]         = make_float4(silu, bs[0], bs[1], bs[2]);
            actp[PLANE + idx] = make_float4(bs[3], bs[4], bs[5], 0.f);
        }
        __syncthreads();

        float acc[O];
#pragma unroll
        for (int o = 0; o < O; ++o) acc[o] = 0.f;

        if (active) {
#pragma unroll 1
            for (int t = 0; t < 9; ++t) {
                const int ky = t / 3, kx = t - ky * 3;
                const int rr = y + ky, col = xx + kx;
                const int idx = fh * CST + rr * RST + (col & 1) * CP + (col >> 1);
                const float4 lo = actp[idx];
                const float4 hi = actp[PLANE + idx];
                const float* wt = wrec + (size_t)(fh * 9 + t) * 8;
#pragma unroll
                for (int o = 0; o < O; ++o) {
                    const float* w = wt + (size_t)o * (F * 8);  // uniform -> s_load
                    acc[o] += lo.x * w[0] + lo.y * w[1] + lo.z * w[2] +
                              lo.w * w[3] + hi.x * w[4] + hi.y * w[5] +
                              hi.z * w[6];
                }
            }
        }

        // channel (fh) reduction into fh==0, 8 floats (2 float4) per round
#pragma unroll
        for (int r = 0; r < O / 8; ++r) {
            __syncthreads();
            if (active) {
                actp[fh * POS + pos]      = make_float4(acc[r*8+0], acc[r*8+1],
                                                        acc[r*8+2], acc[r*8+3]);
                actp[NA + fh * POS + pos] = make_float4(acc[r*8+4], acc[r*8+5],
                                                        acc[r*8+6], acc[r*8+7]);
            }
            __syncthreads();
            if (tid < POS) {
#pragma unroll 2
                for (int fq = 1; fq < FS; ++fq) {
                    const float4 a  = actp[fq * POS + pos];
                    const float4 c4 = actp[NA + fq * POS + pos];
                    acc[r*8+0] += a.x;  acc[r*8+1] += a.y;
                    acc[r*8+2] += a.z;  acc[r*8+3] += a.w;
                    acc[r*8+4] += c4.x; acc[r*8+5] += c4.y;
                    acc[r*8+6] += c4.z; acc[r*8+7] += c4.w;
                }
            }
        }

        // 2x2 maxpool via in-wave shuffles; even (y,x) lanes write h to LDS
        if (tid < POS) {
            const int ph = (v * CR + y) >> 1, pw = xx >> 1;
#pragma unroll
            for (int o = 0; o < O; ++o) {
                float m = acc[o];
                m = fmaxf(m, __shfl_xor(m, 1));
                m = fmaxf(m, __shfl_xor(m, W));
                if (!(lane & 1) && !(lane & W))
                    pool[h_off + (o * PH + ph) * PW + pw] = m;
            }
        }
    }
}

__global__ __launch_bounds__(1024, 4) void kan_all(
        const float* __restrict__ x,
        const float* __restrict__ w1, const float* __restrict__ w2,
        const float* __restrict__ w3,
        const float* __restrict__ lin_w, const float* __restrict__ lin_b,
        float* __restrict__ out) {
    __shared__ float pool[16384];   // 64 KB
    const int tid = threadIdx.x;
    const int b = blockIdx.x;

    // L1: x[b] (3x32x32) -> h1 (8x16x16). act 2*3*351=2106 f4 = 8424 f.
    conv_phase<3, 8, 32, 32, 4, 351, 35, 17, true>(
        pool, x + (size_t)b * 3072, 0, w1, H1_OFF, tid);
    // L2: h1 -> h2 (16x8x8). act 2*8*191=3056 f4 = 12224 f (< H1_OFF).
    conv_phase<8, 16, 16, 16, 2, 191, 19, 9, false>(
        pool, nullptr, H1_OFF, w2, H2_OFF, tid);
    // L3: h2 -> h3 (32x4x4). act 2*16*111=3552 f4 = 14208 f (< H2_OFF; h1 dead).
    conv_phase<16, 32, 8, 8, 1, 111, 11, 5, false>(
        pool, nullptr, H2_OFF, w3, H3_OFF, tid);

    // Linear: out[b, :100] = h3 (512) @ lin_w^T + lin_b
    __syncthreads();
    const int oo = tid >> 3, q = tid & 7;
    float p = 0.f;
    if (oo < 100) {
        const float4* hv = (const float4*)(pool + H3_OFF + q * 64);
        const float4* wv = (const float4*)(lin_w + (size_t)oo * 512 + (size_t)q * 64);
#pragma unroll
        for (int i = 0; i < 16; ++i) {
            float4 a = hv[i], w4 = wv[i];
            p += a.x * w4.x + a.y * w4.y + a.z * w4.z + a.w * w4.w;
        }
        pool[oo * 8 + q] = p;      // region 0 is free now
    }
    __syncthreads();
    if (tid < 100) {
        float s = lin_b[tid];
#pragma unroll
        for (int q2 = 0; q2 < 8; ++q2) s += pool[tid * 8 + q2];
        out[(size_t)b * 100 + tid] = s;
    }
}

extern "C" void kernel_launch(void* const* d_in, const int* in_sizes, int n_in,
                              void* d_out, int out_size, void* d_ws, size_t ws_size,
                              hipStream_t stream) {
    const float* x     = (const float*)d_in[0];
    const float* c1_bw = (const float*)d_in[1];
    const float* c1_sw = (const float*)d_in[2];
    const float* c1_sc = (const float*)d_in[3];
    const float* c2_bw = (const float*)d_in[4];
    const float* c2_sw = (const float*)d_in[5];
    const float* c2_sc = (const float*)d_in[6];
    const float* c3_bw = (const float*)d_in[7];
    const float* c3_sw = (const float*)d_in[8];
    const float* c3_sc = (const float*)d_in[9];
    const float* lin_w = (const float*)d_in[10];
    const float* lin_b = (const float*)d_in[11];
    float* out = (float*)d_out;

    float* ws = (float*)d_ws;
    float* w1 = ws;                 // 216*8  = 1728 floats
    float* w2 = w1 + 1728;          // 1152*8 = 9216
    float* w3 = w2 + 9216;          // 4608*8 = 36864
    // total 47808 floats = 191 KB

    prep_weights<<<24, 256, 0, stream>>>(
        c1_bw, c1_sw, c1_sc, c2_bw, c2_sw, c2_sc, c3_bw, c3_sw, c3_sc,
        w1, w2, w3);

    kan_all<<<256, NTHREADS, 0, stream>>>(x, w1, w2, w3, lin_w, lin_b, out);
}

// Round 9
// 200.438 us; speedup vs baseline: 1.0005x; 1.0005x over previous
//
#include <hip/hip_runtime.h>
#include <math.h>

// ---------------------------------------------------------------------------
// KAN-Conv CIFAR net on gfx950, round 9.
// Per-layer kernels with the round-8 conv engine (LDS act planes, wave-uniform
// channel -> scalar-pipe weight loads, full-O act reuse) PLUS:
//  - exactly 3 __syncthreads per block (stage / taps / scratch write)
//  - fully parallel fused reduce+maxpool: o-major f32 scratch (conflict-free),
//    shfl_xor 2x2 pooling in the read phase, direct global h-store
//  - block LDS sized for multi-block residency per CU (L1 20KB x4, L2 48KB x3,
//    L3 56KB x2) so co-resident blocks hide each other's barrier skew.
// ---------------------------------------------------------------------------

#define BATCH 256

__device__ __forceinline__ void bspline_basis(float x, float bs[6]) {
    const float h = 2.0f / 3.0f;
    float g[10];
#pragma unroll
    for (int i = 0; i < 10; ++i) g[i] = (float)(i - 3) * h - 1.0f;
    float b[9];
#pragma unroll
    for (int i = 0; i < 9; ++i) b[i] = (x >= g[i] && x < g[i + 1]) ? 1.0f : 0.0f;
#pragma unroll
    for (int j = 1; j <= 3; ++j) {
        const float inv_d = 1.0f / ((float)j * h);
#pragma unroll
        for (int i = 0; i + j < 9; ++i) {
            float left  = (x - g[i]) * inv_d;
            float right = (g[i + j + 1] - x) * inv_d;
            b[i] = left * b[i] + right * b[i + 1];
        }
    }
#pragma unroll
    for (int i = 0; i < 6; ++i) bs[i] = b[i];
}

// Fuse {base_w, spline_w*scaler} into 8-float records for all three layers.
__global__ __launch_bounds__(256) void prep_weights(
        const float* __restrict__ bw1, const float* __restrict__ sw1, const float* __restrict__ sc1,
        const float* __restrict__ bw2, const float* __restrict__ sw2, const float* __restrict__ sc2,
        const float* __restrict__ bw3, const float* __restrict__ sw3, const float* __restrict__ sc3,
        float* __restrict__ w1, float* __restrict__ w2, float* __restrict__ w3) {
    int i = blockIdx.x * blockDim.x + threadIdx.x;
    const float *bw, *sw, *sc;
    float* dst;
    int j;
    if (i < 216)       { bw = bw1; sw = sw1; sc = sc1; dst = w1; j = i; }
    else if (i < 1368) { bw = bw2; sw = sw2; sc = sc2; dst = w2; j = i - 216; }
    else if (i < 5976) { bw = bw3; sw = sw3; sc = sc3; dst = w3; j = i - 1368; }
    else return;
    float s = sc[j];
    float4* o = (float4*)(dst + (size_t)j * 8);
    o[0] = make_float4(bw[j], sw[j * 6 + 0] * s, sw[j * 6 + 1] * s, sw[j * 6 + 2] * s);
    o[1] = make_float4(sw[j * 6 + 3] * s, sw[j * 6 + 4] * s, sw[j * 6 + 5] * s, 0.0f);
}

// One fused KAN conv3x3(pad1)+maxpool2 layer.
// Block = (image b, row-strip v of CR conv rows, o-split os of OB channels).
// Thread mapping (taps): tid = fh*POS + pos; fh wave-uniform (POS % 64 == 0),
// handles CPF channels serially; weights via scalar loads.
// Reduce+pool: o-major f32 scratch, all threads, shfl_xor pooling.
template <int C, int O, int OB, int H, int W, int CR, int CPF, int NT, int OS>
__global__ __launch_bounds__(NT, 4) void kan_conv(
        const float* __restrict__ src,    // [B, C, H, W]
        const float* __restrict__ wrec,   // [O, C*9, 8] fused
        float* __restrict__ dst) {        // [B, O, H/2, W/2]
    constexpr int PH = H / 2, PW = W / 2;
    constexpr int VS  = H / CR;
    constexpr int POS = CR * W;            // conv positions per block
    constexpr int FS  = C / CPF;           // fh groups
    constexpr int NA  = FS * POS;          // active tap threads
    constexpr int F   = C * 9;
    constexpr int R   = CR + 2;            // staged rows incl. halo
    constexpr int TC  = W + 2;             // staged cols incl. halo
    constexpr int CP  = TC / 2;            // cols per parity plane
    constexpr int RST = 2 * CP + 1;        // row stride (f4), odd
    constexpr int CST = R * RST;           // channel stride (f4)
    constexpr int PLANE = C * CST;
    constexpr int ACT4  = 2 * PLANE;
    static_assert(POS % 64 == 0, "fh wave-uniform");
    static_assert(NA <= NT, "tap threads fit");
    static_assert(NT % 64 == 0, "wave multiple");
    static_assert(NA * OB <= ACT4 * 4, "scratch fits in act region");
    static_assert((OB * POS) % 64 == 0, "pool groups wave-aligned");

    __shared__ float4 s_act4[ACT4];
    float* scr = (float*)s_act4;

    const int tid = threadIdx.x;
    const int bx  = blockIdx.x;
    const int b   = bx / (VS * OS);
    const int rem = bx % (VS * OS);
    const int v   = rem / OS;
    const int os  = rem % OS;
    const int o0  = os * OB;
    const int r0  = v * CR - 1;            // global row of staged row 0

    // ---- Phase 1: stage zero-padded src -> [silu | b0..b5] act planes
    const float* sb = src + (size_t)b * C * H * W;
    for (int i = tid; i < C * R * TC; i += NT) {
        const int cc  = i / (R * TC);
        const int rr  = (i / TC) % R;
        const int col = i % TC;
        const int gr = r0 + rr, gc = col - 1;
        float val = 0.f;
        if ((unsigned)gr < (unsigned)H && (unsigned)gc < (unsigned)W)
            val = sb[(cc * H + gr) * W + gc];
        const float silu = val / (1.f + __expf(-val));
        float bs[6];
        bspline_basis(val, bs);
        const int idx = cc * CST + rr * RST + (col & 1) * CP + (col >> 1);
        s_act4[idx]         = make_float4(silu, bs[0], bs[1], bs[2]);
        s_act4[PLANE + idx] = make_float4(bs[3], bs[4], bs[5], 0.f);
    }
    __syncthreads();

    // ---- Phase 2: taps. One conv position per thread, OB outputs, CPF chans.
    const int pos = tid % POS;
    const int fh  = __builtin_amdgcn_readfirstlane(tid / POS);
    const int y = pos / W, xx = pos % W;

    float acc[OB];
#pragma unroll
    for (int o = 0; o < OB; ++o) acc[o] = 0.f;

    if (tid < NA) {                        // NA multiple of 64: wave-uniform
#pragma unroll 1
        for (int cp = 0; cp < CPF; ++cp) {
            const int c = fh * CPF + cp;
            const float4* plo = s_act4 + c * CST;
            const float4* phi = plo + PLANE;
            const float* wc = wrec + ((size_t)o0 * F + (size_t)c * 9) * 8;
#pragma unroll 1
            for (int ky = 0; ky < 3; ++ky) {
                const int rr = y + ky;
#pragma unroll
                for (int kx = 0; kx < 3; ++kx) {
                    const int col = xx + kx;
                    const int idx = rr * RST + (col & 1) * CP + (col >> 1);
                    const float4 lo = plo[idx];
                    const float4 hi = phi[idx];
                    const float* wt = wc + (size_t)(ky * 3 + kx) * 8;
#pragma unroll
                    for (int o = 0; o < OB; ++o) {
                        const float* w = wt + (size_t)o * (F * 8);  // scalar
                        acc[o] += lo.x * w[0] + lo.y * w[1] + lo.z * w[2] +
                                  lo.w * w[3] + hi.x * w[4] + hi.y * w[5] +
                                  hi.z * w[6];
                    }
                }
            }
        }
    }
    __syncthreads();                       // act reads done; reuse as scratch

    // ---- Phase 3: write partials, o-major f32 (lane-consecutive -> no conflicts)
    if (tid < NA) {
#pragma unroll
        for (int o = 0; o < OB; ++o)
            scr[(o * FS + fh) * POS + pos] = acc[o];
    }
    __syncthreads();

    // ---- Phase 4: parallel reduce over fh + 2x2 shfl maxpool + global store
    for (int a = tid; a < OB * POS; a += NT) {
        const int oq = a / POS;
        const int p2 = a % POS;
        float s = 0.f;
#pragma unroll
        for (int f = 0; f < FS; ++f) s += scr[(oq * FS + f) * POS + p2];
        s = fmaxf(s, __shfl_xor(s, 1));    // pool over x
        s = fmaxf(s, __shfl_xor(s, W));    // pool over y
        const int yy = p2 / W, xq = p2 % W;
        if (!(xq & 1) && !(yy & 1)) {
            const int ph = (v * CR + yy) >> 1, pw = xq >> 1;
            dst[(((size_t)b * O + o0 + oq) * PH + ph) * PW + pw] = s;
        }
    }
}

// out[n,o] = dot(h[n,:512], w[o,:512]) + bias[o]
__global__ __launch_bounds__(256) void linear_kernel(const float* __restrict__ h,
                                                     const float* __restrict__ w,
                                                     const float* __restrict__ bias,
                                                     float* __restrict__ out) {
    int idx = blockIdx.x * blockDim.x + threadIdx.x;
    if (idx >= BATCH * 100) return;
    int o = idx % 100;
    int n = idx / 100;
    const float4* hp = (const float4*)(h + (size_t)n * 512);
    const float4* wp = (const float4*)(w + (size_t)o * 512);
    float acc = 0.f;
#pragma unroll 4
    for (int i = 0; i < 128; ++i) {
        float4 a = hp[i];
        float4 b = wp[i];
        acc += a.x * b.x + a.y * b.y + a.z * b.z + a.w * b.w;
    }
    out[idx] = acc + bias[o];
}

extern "C" void kernel_launch(void* const* d_in, const int* in_sizes, int n_in,
                              void* d_out, int out_size, void* d_ws, size_t ws_size,
                              hipStream_t stream) {
    const float* x     = (const float*)d_in[0];
    const float* c1_bw = (const float*)d_in[1];
    const float* c1_sw = (const float*)d_in[2];
    const float* c1_sc = (const float*)d_in[3];
    const float* c2_bw = (const float*)d_in[4];
    const float* c2_sw = (const float*)d_in[5];
    const float* c2_sc = (const float*)d_in[6];
    const float* c3_bw = (const float*)d_in[7];
    const float* c3_sw = (const float*)d_in[8];
    const float* c3_sc = (const float*)d_in[9];
    const float* lin_w = (const float*)d_in[10];
    const float* lin_b = (const float*)d_in[11];
    float* out = (float*)d_out;

    float* ws = (float*)d_ws;
    float* h1 = ws;                 // 256*8*16*16  = 524288 floats
    float* h2 = h1 + 524288;        // 256*16*8*8   = 262144
    float* h3 = h2 + 262144;        // 256*32*4*4   = 131072
    float* w1 = h3 + 131072;        // 216*8  = 1728
    float* w2 = w1 + 1728;          // 1152*8 = 9216
    float* w3 = w2 + 9216;          // 4608*8 = 36864
    // total 965312 floats = 3.9 MB

    prep_weights<<<24, 256, 0, stream>>>(
        c1_bw, c1_sw, c1_sc, c2_bw, c2_sw, c2_sc, c3_bw, c3_sw, c3_sc,
        w1, w2, w3);

    // L1: x[256,3,32,32] -> h1[256,8,16,16]
    //     CR=4 (VS=8), CPF=1 (FS=3, NA=384 of 512), LDS ~20KB -> 4 blocks/CU.
    kan_conv<3, 8, 8, 32, 32, 4, 1, 512, 1><<<2048, 512, 0, stream>>>(x, w1, h1);
    // L2: h1 -> h2[256,16,8,8]
    //     CR=8 (VS=2), CPF=2 (FS=4, NA=512), LDS ~48KB -> 3 blocks/CU.
    kan_conv<8, 16, 16, 16, 16, 8, 2, 512, 1><<<512, 512, 0, stream>>>(h1, w2, h2);
    // L3: h2 -> h3[256,32,4,4]
    //     CR=8 (VS=1), CPF=2 (FS=8, NA=512), OS=2 o-halves, LDS ~56KB -> 2/CU.
    kan_conv<16, 32, 16, 8, 8, 8, 2, 512, 2><<<512, 512, 0, stream>>>(h2, w3, h3);
    // Linear: h3[256,512] @ lin_w[100,512]^T + lin_b -> out[256,100]
    linear_kernel<<<100, 256, 0, stream>>>(h3, lin_w, lin_b, out);
}